// Round 1
// baseline (3599.501 us; speedup 1.0000x reference)
//
#include <hip/hip_runtime.h>
#include <hip/hip_bf16.h>

#define NN 50000
#define NE 500000
#define D 64
#define IND 11
#define EDD 4
#define NOD 5
#define NL 4
#define K1 132   // 2D + ED
#define KU 128   // 2D
#define EPSB 1e-5f
#define TE 16

typedef __hip_bfloat16 bf16;

static_assert(NE % TE == 0, "edge tiles");
static_assert(NN % TE == 0, "node tiles");

__device__ __forceinline__ float b2f(bf16 v) { return __bfloat162float(v); }
__device__ __forceinline__ bf16  f2b(float v) { return __float2bfloat16(v); }

__device__ __forceinline__ float ldval(const float* p, int i) { return p[i]; }
__device__ __forceinline__ float ldval(const bf16* p, int i) { return b2f(p[i]); }
// store and return the value as actually stored (keeps BN stats self-consistent)
__device__ __forceinline__ float stval(float* p, int i, float v) { p[i] = v; return v; }
__device__ __forceinline__ float stval(bf16* p, int i, float v) { bf16 t = f2b(v); p[i] = t; return b2f(t); }

// ---------------------------------------------------------------------------
// h = relu(x @ lin_in_w + lin_in_b + prev_h @ hist_w + hist_b)
// ---------------------------------------------------------------------------
__global__ __launch_bounds__(256) void k_input(
    const float* __restrict__ x, const float* __restrict__ prev_h,
    const float* __restrict__ w_in, const float* __restrict__ b_in,
    const float* __restrict__ w_h, const float* __restrict__ b_h,
    float* __restrict__ h)
{
    __shared__ float sW1[IND * D];
    __shared__ float sW2[D * D];
    __shared__ float sb[D];
    __shared__ float sx[4][IND];
    __shared__ float sp[4][D];
    const int tid = threadIdx.x;
    for (int i = tid; i < IND * D; i += 256) sW1[i] = w_in[i];
    for (int i = tid; i < D * D; i += 256) sW2[i] = w_h[i];
    if (tid < D) sb[tid] = b_in[tid] + b_h[tid];
    const int j = tid & 63, r = tid >> 6;
    for (int n0 = blockIdx.x * 4; n0 < NN; n0 += gridDim.x * 4) {
        __syncthreads();
        const int n = n0 + r;
        if (n < NN) {
            sp[r][j] = prev_h[n * D + j];
            if (j < IND) sx[r][j] = x[n * IND + j];
        }
        __syncthreads();
        if (n < NN) {
            float acc = sb[j];
#pragma unroll
            for (int k = 0; k < IND; ++k) acc += sx[r][k] * sW1[k * D + j];
#pragma unroll 8
            for (int k = 0; k < D; ++k) acc += sp[r][k] * sW2[k * D + j];
            h[n * D + j] = fmaxf(acc, 0.0f);
        }
    }
}

// ---------------------------------------------------------------------------
// y[e] = cat(h[dst], h[src], ea) @ W + b  (bf16 store) + column sum/sumsq
// ---------------------------------------------------------------------------
__global__ __launch_bounds__(256) void k_msg1(
    const float* __restrict__ h, const int* __restrict__ src, const int* __restrict__ dst,
    const float* __restrict__ ea,
    const float* __restrict__ W, const float* __restrict__ b,
    bf16* __restrict__ y, float* __restrict__ st)
{
    __shared__ float sW[K1 * D];
    __shared__ __align__(16) float xs[TE][K1];
    __shared__ float red[8][D];
    const int tid = threadIdx.x;
    for (int i = tid; i < K1 * D; i += 256) sW[i] = W[i];
    const int j = tid & 63, g = tid >> 6;
    const float bj = b[j];
    const int half = tid >> 7, lc = tid & 127;
    float ps = 0.f, pq = 0.f;
    for (int t = blockIdx.x; t < NE / TE; t += gridDim.x) {
        const int e0 = t * TE;
        __syncthreads();
#pragma unroll
        for (int rr = 0; rr < TE; rr += 2) {
            const int r = rr + half;
            const int e = e0 + r;
            if (lc < D) xs[r][lc] = h[dst[e] * D + lc];
            else        xs[r][lc] = h[src[e] * D + (lc - D)];
        }
        if (tid < TE * EDD) {
            const int r = tid >> 2, c = tid & 3;
            xs[r][2 * D + c] = ea[(e0 + r) * EDD + c];
        }
        __syncthreads();
        float a0 = bj, a1 = bj, a2 = bj, a3 = bj;
        const float* xr0 = xs[g * 4 + 0];
        const float* xr1 = xs[g * 4 + 1];
        const float* xr2 = xs[g * 4 + 2];
        const float* xr3 = xs[g * 4 + 3];
#pragma unroll
        for (int k = 0; k < K1; k += 4) {
            const float4 x0 = *(const float4*)(xr0 + k);
            const float4 x1 = *(const float4*)(xr1 + k);
            const float4 x2 = *(const float4*)(xr2 + k);
            const float4 x3 = *(const float4*)(xr3 + k);
            const float w0 = sW[(k + 0) * D + j];
            const float w1 = sW[(k + 1) * D + j];
            const float w2 = sW[(k + 2) * D + j];
            const float w3 = sW[(k + 3) * D + j];
            a0 += x0.x * w0; a0 += x0.y * w1; a0 += x0.z * w2; a0 += x0.w * w3;
            a1 += x1.x * w0; a1 += x1.y * w1; a1 += x1.z * w2; a1 += x1.w * w3;
            a2 += x2.x * w0; a2 += x2.y * w1; a2 += x2.z * w2; a2 += x2.w * w3;
            a3 += x3.x * w0; a3 += x3.y * w1; a3 += x3.z * w2; a3 += x3.w * w3;
        }
        const int eb = e0 + g * 4;
        const float f0 = stval(y, (eb + 0) * D + j, a0);
        const float f1 = stval(y, (eb + 1) * D + j, a1);
        const float f2 = stval(y, (eb + 2) * D + j, a2);
        const float f3 = stval(y, (eb + 3) * D + j, a3);
        ps += f0 + f1 + f2 + f3;
        pq += f0 * f0 + f1 * f1 + f2 * f2 + f3 * f3;
    }
    red[g][j] = ps; red[4 + g][j] = pq;
    __syncthreads();
    if (tid < D) {
        atomicAdd(&st[tid],     red[0][tid] + red[1][tid] + red[2][tid] + red[3][tid]);
        atomicAdd(&st[D + tid], red[4][tid] + red[5][tid] + red[6][tid] + red[7][tid]);
    }
}

// ---------------------------------------------------------------------------
// yout = relu(BN(yin)) @ W + b  (in-place safe; T = bf16 edge path or f32 node path)
// ---------------------------------------------------------------------------
template <typename T>
__global__ __launch_bounds__(256) void k_mlp2(
    const T* yin, T* yout,
    const float* __restrict__ W, const float* __restrict__ b,
    const float* __restrict__ gg, const float* __restrict__ be,
    const float* __restrict__ st_in, float* __restrict__ st_out,
    const int ntiles, const float inv_rows_in)
{
    __shared__ float sW[D * D];
    __shared__ float sal[D], sbe[D];
    __shared__ __align__(16) float xs[TE][D];
    __shared__ float red[8][D];
    const int tid = threadIdx.x;
    for (int i = tid; i < D * D; i += 256) sW[i] = W[i];
    if (tid < D) {
        const float m = st_in[tid] * inv_rows_in;
        const float v = st_in[D + tid] * inv_rows_in - m * m;
        const float a = rsqrtf(v + EPSB) * gg[tid];
        sal[tid] = a;
        sbe[tid] = be[tid] - m * a;
    }
    const int j = tid & 63, g = tid >> 6;
    const float bj = b[j];
    float ps = 0.f, pq = 0.f;
    for (int t = blockIdx.x; t < ntiles; t += gridDim.x) {
        const int r0 = t * TE;
        __syncthreads();
#pragma unroll
        for (int i = tid; i < TE * D; i += 256) {
            const int rr = i >> 6, c = i & 63;
            xs[rr][c] = fmaxf(ldval(yin, (r0 + rr) * D + c) * sal[c] + sbe[c], 0.f);
        }
        __syncthreads();
        float a0 = bj, a1 = bj, a2 = bj, a3 = bj;
        const float* xr0 = xs[g * 4 + 0];
        const float* xr1 = xs[g * 4 + 1];
        const float* xr2 = xs[g * 4 + 2];
        const float* xr3 = xs[g * 4 + 3];
#pragma unroll
        for (int k = 0; k < D; k += 4) {
            const float4 x0 = *(const float4*)(xr0 + k);
            const float4 x1 = *(const float4*)(xr1 + k);
            const float4 x2 = *(const float4*)(xr2 + k);
            const float4 x3 = *(const float4*)(xr3 + k);
            const float w0 = sW[(k + 0) * D + j];
            const float w1 = sW[(k + 1) * D + j];
            const float w2 = sW[(k + 2) * D + j];
            const float w3 = sW[(k + 3) * D + j];
            a0 += x0.x * w0; a0 += x0.y * w1; a0 += x0.z * w2; a0 += x0.w * w3;
            a1 += x1.x * w0; a1 += x1.y * w1; a1 += x1.z * w2; a1 += x1.w * w3;
            a2 += x2.x * w0; a2 += x2.y * w1; a2 += x2.z * w2; a2 += x2.w * w3;
            a3 += x3.x * w0; a3 += x3.y * w1; a3 += x3.z * w2; a3 += x3.w * w3;
        }
        const int rb = r0 + g * 4;
        const float f0 = stval(yout, (rb + 0) * D + j, a0);
        const float f1 = stval(yout, (rb + 1) * D + j, a1);
        const float f2 = stval(yout, (rb + 2) * D + j, a2);
        const float f3 = stval(yout, (rb + 3) * D + j, a3);
        ps += f0 + f1 + f2 + f3;
        pq += f0 * f0 + f1 * f1 + f2 * f2 + f3 * f3;
    }
    red[g][j] = ps; red[4 + g][j] = pq;
    __syncthreads();
    if (tid < D) {
        atomicAdd(&st_out[tid],     red[0][tid] + red[1][tid] + red[2][tid] + red[3][tid]);
        atomicAdd(&st_out[D + tid], red[4][tid] + red[5][tid] + red[6][tid] + red[7][tid]);
    }
}

// ---------------------------------------------------------------------------
// aggr[dst[e]] += relu(BN2(y[e]))   (fp32 atomics, skip zeros)
// ---------------------------------------------------------------------------
__global__ __launch_bounds__(256) void k_aggr(
    const bf16* __restrict__ y, const int* __restrict__ dst,
    const float* __restrict__ gg, const float* __restrict__ be,
    const float* __restrict__ st, float* __restrict__ aggr)
{
    __shared__ float sal[D], sbe[D];
    const int tid = threadIdx.x;
    if (tid < D) {
        const float m = st[tid] * (1.f / NE);
        const float v = st[D + tid] * (1.f / NE) - m * m;
        const float a = rsqrtf(v + EPSB) * gg[tid];
        sal[tid] = a;
        sbe[tid] = be[tid] - m * a;
    }
    __syncthreads();
    const int j = tid & 63;
    const float al = sal[j], bt = sbe[j];
    const int total = NE * D;
    for (int i = blockIdx.x * 256 + tid; i < total; i += gridDim.x * 256) {
        const int e = i >> 6;
        const float val = fmaxf(b2f(y[i]) * al + bt, 0.f);
        if (val != 0.f) atomicAdd(&aggr[dst[e] * D + j], val);
    }
}

// ---------------------------------------------------------------------------
// z = cat(h, aggr) @ W + b + stats
// ---------------------------------------------------------------------------
__global__ __launch_bounds__(256) void k_upd1(
    const float* __restrict__ h, const float* __restrict__ aggr,
    const float* __restrict__ W, const float* __restrict__ b,
    float* __restrict__ z, float* __restrict__ st)
{
    __shared__ float sW[KU * D];
    __shared__ __align__(16) float xs[TE][KU];
    __shared__ float red[8][D];
    const int tid = threadIdx.x;
    for (int i = tid; i < KU * D; i += 256) sW[i] = W[i];
    const int j = tid & 63, g = tid >> 6;
    const float bj = b[j];
    const int half = tid >> 7, lc = tid & 127;
    float ps = 0.f, pq = 0.f;
    for (int t = blockIdx.x; t < NN / TE; t += gridDim.x) {
        const int n0 = t * TE;
        __syncthreads();
#pragma unroll
        for (int rr = 0; rr < TE; rr += 2) {
            const int r = rr + half;
            const int n = n0 + r;
            xs[r][lc] = (lc < D) ? h[n * D + lc] : aggr[n * D + (lc - D)];
        }
        __syncthreads();
        float a0 = bj, a1 = bj, a2 = bj, a3 = bj;
        const float* xr0 = xs[g * 4 + 0];
        const float* xr1 = xs[g * 4 + 1];
        const float* xr2 = xs[g * 4 + 2];
        const float* xr3 = xs[g * 4 + 3];
#pragma unroll
        for (int k = 0; k < KU; k += 4) {
            const float4 x0 = *(const float4*)(xr0 + k);
            const float4 x1 = *(const float4*)(xr1 + k);
            const float4 x2 = *(const float4*)(xr2 + k);
            const float4 x3 = *(const float4*)(xr3 + k);
            const float w0 = sW[(k + 0) * D + j];
            const float w1 = sW[(k + 1) * D + j];
            const float w2 = sW[(k + 2) * D + j];
            const float w3 = sW[(k + 3) * D + j];
            a0 += x0.x * w0; a0 += x0.y * w1; a0 += x0.z * w2; a0 += x0.w * w3;
            a1 += x1.x * w0; a1 += x1.y * w1; a1 += x1.z * w2; a1 += x1.w * w3;
            a2 += x2.x * w0; a2 += x2.y * w1; a2 += x2.z * w2; a2 += x2.w * w3;
            a3 += x3.x * w0; a3 += x3.y * w1; a3 += x3.z * w2; a3 += x3.w * w3;
        }
        const int nb = n0 + g * 4;
        const float f0 = stval(z, (nb + 0) * D + j, a0);
        const float f1 = stval(z, (nb + 1) * D + j, a1);
        const float f2 = stval(z, (nb + 2) * D + j, a2);
        const float f3 = stval(z, (nb + 3) * D + j, a3);
        ps += f0 + f1 + f2 + f3;
        pq += f0 * f0 + f1 * f1 + f2 * f2 + f3 * f3;
    }
    red[g][j] = ps; red[4 + g][j] = pq;
    __syncthreads();
    if (tid < D) {
        atomicAdd(&st[tid],     red[0][tid] + red[1][tid] + red[2][tid] + red[3][tid]);
        atomicAdd(&st[D + tid], red[4][tid] + red[5][tid] + red[6][tid] + red[7][tid]);
    }
}

// ---------------------------------------------------------------------------
// h += relu(BN(z))
// ---------------------------------------------------------------------------
__global__ __launch_bounds__(256) void k_upd3(
    const float* __restrict__ z, const float* __restrict__ gg, const float* __restrict__ be,
    const float* __restrict__ st, float* __restrict__ h)
{
    __shared__ float sal[D], sbe[D];
    const int tid = threadIdx.x;
    if (tid < D) {
        const float m = st[tid] * (1.f / NN);
        const float v = st[D + tid] * (1.f / NN) - m * m;
        const float a = rsqrtf(v + EPSB) * gg[tid];
        sal[tid] = a;
        sbe[tid] = be[tid] - m * a;
    }
    __syncthreads();
    const int j = tid & 63;
    const float al = sal[j], bt = sbe[j];
    for (int i = blockIdx.x * 256 + tid; i < NN * D; i += gridDim.x * 256) {
        h[i] += fmaxf(z[i] * al + bt, 0.f);
    }
}

// ---------------------------------------------------------------------------
// node_out = h @ node_w + node_b ; hsum += column sums of h ; copy h to d_out
// ---------------------------------------------------------------------------
__global__ __launch_bounds__(256) void k_nodeout(
    const float* __restrict__ h, const float* __restrict__ nw, const float* __restrict__ nb,
    float* __restrict__ node_out, float* __restrict__ h_out, float* __restrict__ hsum)
{
    __shared__ float hs[64][65];
    __shared__ float snw[D * NOD];
    __shared__ float snb[NOD];
    __shared__ float red[4][D];
    const int tid = threadIdx.x;
    for (int i = tid; i < D * NOD; i += 256) snw[i] = nw[i];
    if (tid < NOD) snb[tid] = nb[tid];
    const int j = tid & 63, g = tid >> 6;
    float cs = 0.f;
    for (int n0 = blockIdx.x * 64; n0 < NN; n0 += gridDim.x * 64) {
        __syncthreads();
        for (int r = g; r < 64; r += 4) {
            const int n = n0 + r;
            float v = 0.f;
            if (n < NN) { v = h[n * D + j]; h_out[n * D + j] = v; }
            hs[r][j] = v;
        }
        __syncthreads();
        for (int r = g; r < 64; r += 4) cs += hs[r][j];
        for (int it = tid; it < 64 * NOD; it += 256) {
            const int r = it / NOD, c = it - r * NOD;
            const int n = n0 + r;
            if (n < NN) {
                float a = snb[c];
#pragma unroll 16
                for (int k = 0; k < D; ++k) a += hs[r][k] * snw[k * NOD + c];
                node_out[n * NOD + c] = a;
            }
        }
    }
    red[g][j] = cs;
    __syncthreads();
    if (tid < D) atomicAdd(&hsum[tid], red[0][tid] + red[1][tid] + red[2][tid] + red[3][tid]);
}

__global__ void k_graphout(const float* __restrict__ hsum, const float* __restrict__ gw,
                           const float* __restrict__ gb, float* __restrict__ out)
{
    const int j = threadIdx.x;  // 64 threads
    float v = hsum[j] * (1.f / NN) * gw[j];
#pragma unroll
    for (int off = 32; off > 0; off >>= 1) v += __shfl_down(v, off, 64);
    if (j == 0) out[0] = v + gb[0];
}

// ---------------------------------------------------------------------------
extern "C" void kernel_launch(void* const* d_in, const int* in_sizes, int n_in,
                              void* d_out, int out_size, void* d_ws, size_t ws_size,
                              hipStream_t stream)
{
    (void)in_sizes; (void)n_in; (void)out_size; (void)ws_size;
    const float* x        = (const float*)d_in[0];
    const int*   ei       = (const int*)  d_in[1];
    const float* ea       = (const float*)d_in[2];
    const float* prev_h   = (const float*)d_in[3];
    const float* lin_in_w = (const float*)d_in[4];
    const float* lin_in_b = (const float*)d_in[5];
    const float* hist_w   = (const float*)d_in[6];
    const float* hist_b   = (const float*)d_in[7];
    const float* msg_w1   = (const float*)d_in[8];
    const float* msg_b1   = (const float*)d_in[9];
    const float* msg_g1   = (const float*)d_in[10];
    const float* msg_be1  = (const float*)d_in[11];
    const float* msg_w2   = (const float*)d_in[12];
    const float* msg_b2   = (const float*)d_in[13];
    const float* msg_g2   = (const float*)d_in[14];
    const float* msg_be2  = (const float*)d_in[15];
    const float* upd_w1   = (const float*)d_in[16];
    const float* upd_b1   = (const float*)d_in[17];
    const float* upd_g1   = (const float*)d_in[18];
    const float* upd_be1  = (const float*)d_in[19];
    const float* upd_w2   = (const float*)d_in[20];
    const float* upd_b2   = (const float*)d_in[21];
    const float* upd_g2   = (const float*)d_in[22];
    const float* upd_be2  = (const float*)d_in[23];
    const float* graph_w  = (const float*)d_in[24];
    const float* graph_b  = (const float*)d_in[25];
    const float* node_w   = (const float*)d_in[26];
    const float* node_b   = (const float*)d_in[27];

    const int* src = ei;        // edge_index[0]
    const int* dst = ei + NE;   // edge_index[1]

    float* out       = (float*)d_out;
    float* graph_out = out;                  // [1]
    float* node_out  = out + 1;              // [N*NO]
    float* h_out     = out + 1 + NN * NOD;   // [N*D]

    char* ws = (char*)d_ws;
    size_t off = 0;
    bf16*  y    = (bf16*)(ws + off);  off += (size_t)NE * D * sizeof(bf16);   // 64 MB
    float* aggr = (float*)(ws + off); off += (size_t)NN * D * sizeof(float);  // 12.8 MB
    float* z    = (float*)(ws + off); off += (size_t)NN * D * sizeof(float);  // 12.8 MB
    float* h    = (float*)(ws + off); off += (size_t)NN * D * sizeof(float);  // 12.8 MB
    float* stats = (float*)(ws + off);   // [NL][4][2][D] then hsum[D]
    float* hsum  = stats + NL * 4 * 2 * D;
    const size_t stats_bytes = (NL * 4 * 2 * D + D) * sizeof(float);

    hipMemsetAsync(stats, 0, stats_bytes, stream);
    k_input<<<512, 256, 0, stream>>>(x, prev_h, lin_in_w, lin_in_b, hist_w, hist_b, h);

    for (int l = 0; l < NL; ++l) {
        float* st_m1 = stats + (l * 4 + 0) * 2 * D;
        float* st_m2 = stats + (l * 4 + 1) * 2 * D;
        float* st_u1 = stats + (l * 4 + 2) * 2 * D;
        float* st_u2 = stats + (l * 4 + 3) * 2 * D;
        k_msg1<<<1024, 256, 0, stream>>>(h, src, dst, ea,
                                         msg_w1 + (size_t)l * K1 * D, msg_b1 + l * D, y, st_m1);
        k_mlp2<bf16><<<1024, 256, 0, stream>>>(y, y,
                                               msg_w2 + (size_t)l * D * D, msg_b2 + l * D,
                                               msg_g1 + l * D, msg_be1 + l * D,
                                               st_m1, st_m2, NE / TE, 1.f / NE);
        hipMemsetAsync(aggr, 0, (size_t)NN * D * sizeof(float), stream);
        k_aggr<<<2048, 256, 0, stream>>>(y, dst, msg_g2 + l * D, msg_be2 + l * D, st_m2, aggr);
        k_upd1<<<512, 256, 0, stream>>>(h, aggr,
                                        upd_w1 + (size_t)l * KU * D, upd_b1 + l * D, z, st_u1);
        k_mlp2<float><<<512, 256, 0, stream>>>(z, z,
                                               upd_w2 + (size_t)l * D * D, upd_b2 + l * D,
                                               upd_g1 + l * D, upd_be1 + l * D,
                                               st_u1, st_u2, NN / TE, 1.f / NN);
        k_upd3<<<1024, 256, 0, stream>>>(z, upd_g2 + l * D, upd_be2 + l * D, st_u2, h);
    }

    k_nodeout<<<782, 256, 0, stream>>>(h, node_w, node_b, node_out, h_out, hsum);
    k_graphout<<<1, 64, 0, stream>>>(hsum, graph_w, graph_b, graph_out);
}

// Round 2
// 1274.380 us; speedup vs baseline: 2.8245x; 2.8245x over previous
//
#include <hip/hip_runtime.h>
#include <hip/hip_bf16.h>

#define NN 50000
#define NE 500000
#define D 64
#define IND 11
#define EDD 4
#define NOD 5
#define NL 4
#define K1 132   // 2D + ED
#define KU 128   // 2D
#define EPSB 1e-5f

#define LDA1 168  // K-stride (bf16) for msg1 tiles: 160 used + 8 pad
#define LDA2 72   // K=64 + 8
#define LDA3 136  // K=128 + 8

typedef __hip_bfloat16 bf16;
typedef __attribute__((ext_vector_type(8))) __bf16 bf16x8;
typedef __attribute__((ext_vector_type(4))) float f32x4;

__device__ __forceinline__ ushort f2u(float f) {
    __hip_bfloat16 h = __float2bfloat16(f);
    return __builtin_bit_cast(ushort, h);
}
__device__ __forceinline__ float u2f(ushort u) {
    uint v = (uint)u << 16;
    return __builtin_bit_cast(float, v);
}

// ---------------------------------------------------------------------------
// h = relu(x @ lin_in_w + b + prev_h @ hist_w + b) ; hb = bf16(h)
// ---------------------------------------------------------------------------
__global__ __launch_bounds__(256) void k_input(
    const float* __restrict__ x, const float* __restrict__ prev_h,
    const float* __restrict__ w_in, const float* __restrict__ b_in,
    const float* __restrict__ w_h, const float* __restrict__ b_h,
    float* __restrict__ h, ushort* __restrict__ hb)
{
    __shared__ float sW1[IND * D];
    __shared__ float sW2[D * D];
    __shared__ float sb[D];
    __shared__ float sx[4][IND];
    __shared__ float sp[4][D];
    const int tid = threadIdx.x;
    for (int i = tid; i < IND * D; i += 256) sW1[i] = w_in[i];
    for (int i = tid; i < D * D; i += 256) sW2[i] = w_h[i];
    if (tid < D) sb[tid] = b_in[tid] + b_h[tid];
    const int j = tid & 63, r = tid >> 6;
    for (int n0 = blockIdx.x * 4; n0 < NN; n0 += gridDim.x * 4) {
        __syncthreads();
        const int n = n0 + r;
        if (n < NN) {
            sp[r][j] = prev_h[n * D + j];
            if (j < IND) sx[r][j] = x[n * IND + j];
        }
        __syncthreads();
        if (n < NN) {
            float acc = sb[j];
#pragma unroll
            for (int k = 0; k < IND; ++k) acc += sx[r][k] * sW1[k * D + j];
#pragma unroll 8
            for (int k = 0; k < D; ++k) acc += sp[r][k] * sW2[k * D + j];
            const float v = fmaxf(acc, 0.0f);
            h[n * D + j] = v;
            hb[n * D + j] = f2u(v);
        }
    }
}

// ---------------------------------------------------------------------------
// y[e] = cat(hb[dst], hb[src], ea) @ W + b   (MFMA, bf16 out) + column stats
// ---------------------------------------------------------------------------
__global__ __launch_bounds__(256, 2) void k_msg1(
    const ushort* __restrict__ hb, const int* __restrict__ src, const int* __restrict__ dst,
    const float* __restrict__ ea,
    const float* __restrict__ W, const float* __restrict__ b,
    ushort* __restrict__ y, float* __restrict__ st)
{
    __shared__ __align__(16) ushort xs[64][LDA1];
    __shared__ __align__(16) ushort wt[64][LDA1];
    __shared__ float sred[4][2][64];
    const int tid = threadIdx.x;
    const int lane = tid & 63, w = tid >> 6;
    const int fn = lane & 15, quad = lane >> 4;

    // one-time: zero wt, stage W^T (bf16), zero xs K-pad region [128..LDA1)
    for (int i = tid; i < 64 * LDA1; i += 256) ((ushort*)wt)[i] = 0;
    for (int i = tid; i < 64 * (LDA1 - 128); i += 256) {
        const int r = i / (LDA1 - 128), k = 128 + i % (LDA1 - 128);
        xs[r][k] = 0;
    }
    __syncthreads();
    for (int i = tid; i < K1 * D; i += 256) {
        const int k = i >> 6, n = i & 63;
        wt[n][k] = f2u(W[i]);
    }
    __syncthreads();

    // B fragments to registers: Bf[s][c] covers k=s*32.., cols c*16..
    bf16x8 Bf[5][4];
#pragma unroll
    for (int s = 0; s < 5; ++s)
#pragma unroll
        for (int c = 0; c < 4; ++c)
            Bf[s][c] = *(const bf16x8*)&wt[c * 16 + fn][s * 32 + quad * 8];
    float bj[4];
#pragma unroll
    for (int c = 0; c < 4; ++c) bj[c] = b[c * 16 + fn];

    float ps[4] = {0, 0, 0, 0}, pq[4] = {0, 0, 0, 0};
    const int r = tid >> 2, q = tid & 3;   // staging: row r, col-chunk q*16
    const int ntiles = (NE + 63) >> 6;

    for (int t = blockIdx.x; t < ntiles; t += gridDim.x) {
        const int e0 = t << 6;
        __syncthreads();
        const int e = e0 + r;
        if (e < NE) {
            const int di = dst[e], si = src[e];
            const uint4 a0 = *(const uint4*)&hb[(size_t)di * D + q * 16];
            const uint4 a1 = *(const uint4*)&hb[(size_t)di * D + q * 16 + 8];
            const uint4 b0 = *(const uint4*)&hb[(size_t)si * D + q * 16];
            const uint4 b1 = *(const uint4*)&hb[(size_t)si * D + q * 16 + 8];
            *(uint4*)&xs[r][q * 16] = a0;
            *(uint4*)&xs[r][q * 16 + 8] = a1;
            *(uint4*)&xs[r][64 + q * 16] = b0;
            *(uint4*)&xs[r][64 + q * 16 + 8] = b1;
            if (q == 0) {
                const float4 t4 = *(const float4*)&ea[(size_t)e * EDD];
                uint2 p;
                p.x = (uint)f2u(t4.x) | ((uint)f2u(t4.y) << 16);
                p.y = (uint)f2u(t4.z) | ((uint)f2u(t4.w) << 16);
                *(uint2*)&xs[r][128] = p;
            }
        } else {
            const uint4 z4 = {0, 0, 0, 0};
            *(uint4*)&xs[r][q * 16] = z4;
            *(uint4*)&xs[r][q * 16 + 8] = z4;
            *(uint4*)&xs[r][64 + q * 16] = z4;
            *(uint4*)&xs[r][64 + q * 16 + 8] = z4;
            if (q == 0) { const uint2 z2 = {0, 0}; *(uint2*)&xs[r][128] = z2; }
        }
        __syncthreads();

        f32x4 acc[4];
#pragma unroll
        for (int c = 0; c < 4; ++c) acc[c] = (f32x4){bj[c], bj[c], bj[c], bj[c]};
        const ushort* arow = xs[w * 16 + fn];
#pragma unroll
        for (int s = 0; s < 5; ++s) {
            const bf16x8 a = *(const bf16x8*)&arow[s * 32 + quad * 8];
            acc[0] = __builtin_amdgcn_mfma_f32_16x16x32_bf16(a, Bf[s][0], acc[0], 0, 0, 0);
            acc[1] = __builtin_amdgcn_mfma_f32_16x16x32_bf16(a, Bf[s][1], acc[1], 0, 0, 0);
            acc[2] = __builtin_amdgcn_mfma_f32_16x16x32_bf16(a, Bf[s][2], acc[2], 0, 0, 0);
            acc[3] = __builtin_amdgcn_mfma_f32_16x16x32_bf16(a, Bf[s][3], acc[3], 0, 0, 0);
        }
        const int row0 = e0 + w * 16 + quad * 4;
#pragma unroll
        for (int reg = 0; reg < 4; ++reg) {
            const int er = row0 + reg;
            if (er < NE) {
#pragma unroll
                for (int c = 0; c < 4; ++c) {
                    const ushort ub = f2u(acc[c][reg]);
                    y[(size_t)er * D + c * 16 + fn] = ub;
                    const float f = u2f(ub);
                    ps[c] += f; pq[c] += f * f;
                }
            }
        }
    }
    __syncthreads();
#pragma unroll
    for (int c = 0; c < 4; ++c) {
        ps[c] += __shfl_xor(ps[c], 16, 64); ps[c] += __shfl_xor(ps[c], 32, 64);
        pq[c] += __shfl_xor(pq[c], 16, 64); pq[c] += __shfl_xor(pq[c], 32, 64);
    }
    if (quad == 0) {
#pragma unroll
        for (int c = 0; c < 4; ++c) {
            sred[w][0][c * 16 + fn] = ps[c];
            sred[w][1][c * 16 + fn] = pq[c];
        }
    }
    __syncthreads();
    if (tid < 128) {
        const int col = tid & 63, which = tid >> 6;
        const float s = sred[0][which][col] + sred[1][which][col] +
                        sred[2][which][col] + sred[3][which][col];
        atomicAdd(&st[which * 64 + col], s);
    }
}

// ---------------------------------------------------------------------------
// yout = relu(BN(yin)) @ W + b   (MFMA, bf16 in/out, in-place safe) + stats
// ---------------------------------------------------------------------------
__global__ __launch_bounds__(256, 2) void k_mlp2b(
    const ushort* __restrict__ yin, ushort* __restrict__ yout,
    const float* __restrict__ W, const float* __restrict__ b,
    const float* __restrict__ gg, const float* __restrict__ be,
    const float* __restrict__ st_in, float* __restrict__ st_out,
    const int nrows, const float inv_rows)
{
    __shared__ __align__(16) ushort xs[64][LDA2];
    __shared__ __align__(16) ushort wt[64][LDA2];
    __shared__ float sal[64], sbe[64];
    __shared__ float sred[4][2][64];
    const int tid = threadIdx.x;
    const int lane = tid & 63, w = tid >> 6;
    const int fn = lane & 15, quad = lane >> 4;

    if (tid < 64) {
        const float m = st_in[tid] * inv_rows;
        const float v = st_in[64 + tid] * inv_rows - m * m;
        const float a = rsqrtf(v + EPSB) * gg[tid];
        sal[tid] = a;
        sbe[tid] = be[tid] - m * a;
    }
    for (int i = tid; i < D * D; i += 256) {
        const int k = i >> 6, n = i & 63;
        wt[n][k] = f2u(W[i]);
    }
    __syncthreads();

    bf16x8 Bf[2][4];
#pragma unroll
    for (int s = 0; s < 2; ++s)
#pragma unroll
        for (int c = 0; c < 4; ++c)
            Bf[s][c] = *(const bf16x8*)&wt[c * 16 + fn][s * 32 + quad * 8];
    float bj[4];
#pragma unroll
    for (int c = 0; c < 4; ++c) bj[c] = b[c * 16 + fn];

    const int r = tid >> 2, q = tid & 3;  // staging: row r, cols q*16..q*16+15
    float al16[16], be16[16];
#pragma unroll
    for (int i = 0; i < 16; ++i) { al16[i] = sal[q * 16 + i]; be16[i] = sbe[q * 16 + i]; }

    float ps[4] = {0, 0, 0, 0}, pq[4] = {0, 0, 0, 0};
    const int ntiles = (nrows + 63) >> 6;

    for (int t = blockIdx.x; t < ntiles; t += gridDim.x) {
        const int r0 = t << 6;
        __syncthreads();
        const int row = r0 + r;
        if (row < nrows) {
            const uint4 u0 = *(const uint4*)&yin[(size_t)row * D + q * 16];
            const uint4 u1 = *(const uint4*)&yin[(size_t)row * D + q * 16 + 8];
            uint res0[4], res1[4];
#pragma unroll
            for (int p = 0; p < 4; ++p) {
                const uint uu = ((const uint*)&u0)[p];
                float f0 = u2f((ushort)(uu & 0xffffu));
                float f1 = u2f((ushort)(uu >> 16));
                f0 = fmaxf(fmaf(f0, al16[2 * p], be16[2 * p]), 0.f);
                f1 = fmaxf(fmaf(f1, al16[2 * p + 1], be16[2 * p + 1]), 0.f);
                res0[p] = (uint)f2u(f0) | ((uint)f2u(f1) << 16);
            }
#pragma unroll
            for (int p = 0; p < 4; ++p) {
                const uint uu = ((const uint*)&u1)[p];
                float f0 = u2f((ushort)(uu & 0xffffu));
                float f1 = u2f((ushort)(uu >> 16));
                f0 = fmaxf(fmaf(f0, al16[8 + 2 * p], be16[8 + 2 * p]), 0.f);
                f1 = fmaxf(fmaf(f1, al16[8 + 2 * p + 1], be16[8 + 2 * p + 1]), 0.f);
                res1[p] = (uint)f2u(f0) | ((uint)f2u(f1) << 16);
            }
            *(uint4*)&xs[r][q * 16] = *(uint4*)res0;
            *(uint4*)&xs[r][q * 16 + 8] = *(uint4*)res1;
        } else {
            const uint4 z4 = {0, 0, 0, 0};
            *(uint4*)&xs[r][q * 16] = z4;
            *(uint4*)&xs[r][q * 16 + 8] = z4;
        }
        __syncthreads();

        f32x4 acc[4];
#pragma unroll
        for (int c = 0; c < 4; ++c) acc[c] = (f32x4){bj[c], bj[c], bj[c], bj[c]};
        const ushort* arow = xs[w * 16 + fn];
#pragma unroll
        for (int s = 0; s < 2; ++s) {
            const bf16x8 a = *(const bf16x8*)&arow[s * 32 + quad * 8];
            acc[0] = __builtin_amdgcn_mfma_f32_16x16x32_bf16(a, Bf[s][0], acc[0], 0, 0, 0);
            acc[1] = __builtin_amdgcn_mfma_f32_16x16x32_bf16(a, Bf[s][1], acc[1], 0, 0, 0);
            acc[2] = __builtin_amdgcn_mfma_f32_16x16x32_bf16(a, Bf[s][2], acc[2], 0, 0, 0);
            acc[3] = __builtin_amdgcn_mfma_f32_16x16x32_bf16(a, Bf[s][3], acc[3], 0, 0, 0);
        }
        const int row0 = r0 + w * 16 + quad * 4;
#pragma unroll
        for (int reg = 0; reg < 4; ++reg) {
            const int er = row0 + reg;
            if (er < nrows) {
#pragma unroll
                for (int c = 0; c < 4; ++c) {
                    const ushort ub = f2u(acc[c][reg]);
                    yout[(size_t)er * D + c * 16 + fn] = ub;
                    const float f = u2f(ub);
                    ps[c] += f; pq[c] += f * f;
                }
            }
        }
    }
    __syncthreads();
#pragma unroll
    for (int c = 0; c < 4; ++c) {
        ps[c] += __shfl_xor(ps[c], 16, 64); ps[c] += __shfl_xor(ps[c], 32, 64);
        pq[c] += __shfl_xor(pq[c], 16, 64); pq[c] += __shfl_xor(pq[c], 32, 64);
    }
    if (quad == 0) {
#pragma unroll
        for (int c = 0; c < 4; ++c) {
            sred[w][0][c * 16 + fn] = ps[c];
            sred[w][1][c * 16 + fn] = pq[c];
        }
    }
    __syncthreads();
    if (tid < 128) {
        const int col = tid & 63, which = tid >> 6;
        const float s = sred[0][which][col] + sred[1][which][col] +
                        sred[2][which][col] + sred[3][which][col];
        atomicAdd(&st_out[which * 64 + col], s);
    }
}

// ---------------------------------------------------------------------------
// aggr[dst[e]] += relu(BN2(y[e]))   (fp32 atomics, skip zeros)
// ---------------------------------------------------------------------------
__global__ __launch_bounds__(256) void k_aggr(
    const ushort* __restrict__ y, const int* __restrict__ dst,
    const float* __restrict__ gg, const float* __restrict__ be,
    const float* __restrict__ st, float* __restrict__ aggr)
{
    __shared__ float sal[D], sbe[D];
    const int tid = threadIdx.x;
    if (tid < D) {
        const float m = st[tid] * (1.f / NE);
        const float v = st[D + tid] * (1.f / NE) - m * m;
        const float a = rsqrtf(v + EPSB) * gg[tid];
        sal[tid] = a;
        sbe[tid] = be[tid] - m * a;
    }
    __syncthreads();
    const int j = tid & 63;
    const float al = sal[j], bt = sbe[j];
    const int total = NE * D;
    for (int i = blockIdx.x * 256 + tid; i < total; i += gridDim.x * 256) {
        const int e = i >> 6;
        const float val = fmaxf(fmaf(u2f(y[i]), al, bt), 0.f);
        if (val != 0.f) atomicAdd(&aggr[dst[e] * D + j], val);
    }
}

// ---------------------------------------------------------------------------
// z = cat(h, aggr) @ W + b   (MFMA, fp32 inputs -> bf16 staged) + stats
// ---------------------------------------------------------------------------
__global__ __launch_bounds__(256, 2) void k_upd1(
    const float* __restrict__ h, const float* __restrict__ aggr,
    const float* __restrict__ W, const float* __restrict__ b,
    ushort* __restrict__ z, float* __restrict__ st)
{
    __shared__ __align__(16) ushort xs[64][LDA3];
    __shared__ __align__(16) ushort wt[64][LDA3];
    __shared__ float sred[4][2][64];
    const int tid = threadIdx.x;
    const int lane = tid & 63, w = tid >> 6;
    const int fn = lane & 15, quad = lane >> 4;

    for (int i = tid; i < KU * D; i += 256) {
        const int k = i >> 6, n = i & 63;
        wt[n][k] = f2u(W[i]);
    }
    __syncthreads();

    bf16x8 Bf[4][4];
#pragma unroll
    for (int s = 0; s < 4; ++s)
#pragma unroll
        for (int c = 0; c < 4; ++c)
            Bf[s][c] = *(const bf16x8*)&wt[c * 16 + fn][s * 32 + quad * 8];
    float bj[4];
#pragma unroll
    for (int c = 0; c < 4; ++c) bj[c] = b[c * 16 + fn];

    const int r = tid >> 2, q = tid & 3;
    float ps[4] = {0, 0, 0, 0}, pq[4] = {0, 0, 0, 0};
    const int ntiles = (NN + 63) >> 6;

    for (int t = blockIdx.x; t < ntiles; t += gridDim.x) {
        const int n0 = t << 6;
        __syncthreads();
        const int n = n0 + r;
        if (n < NN) {
            uint out0[4], out1[4], out2[4], out3[4];
#pragma unroll
            for (int p = 0; p < 4; ++p) {
                const float4 hv = *(const float4*)&h[(size_t)n * D + q * 16 + p * 4];
                ((uint*)(p < 2 ? out0 : out1))[(p & 1) * 2 + 0] =
                    (uint)f2u(hv.x) | ((uint)f2u(hv.y) << 16);
                ((uint*)(p < 2 ? out0 : out1))[(p & 1) * 2 + 1] =
                    (uint)f2u(hv.z) | ((uint)f2u(hv.w) << 16);
            }
#pragma unroll
            for (int p = 0; p < 4; ++p) {
                const float4 av = *(const float4*)&aggr[(size_t)n * D + q * 16 + p * 4];
                ((uint*)(p < 2 ? out2 : out3))[(p & 1) * 2 + 0] =
                    (uint)f2u(av.x) | ((uint)f2u(av.y) << 16);
                ((uint*)(p < 2 ? out2 : out3))[(p & 1) * 2 + 1] =
                    (uint)f2u(av.z) | ((uint)f2u(av.w) << 16);
            }
            *(uint4*)&xs[r][q * 16] = *(uint4*)out0;
            *(uint4*)&xs[r][q * 16 + 8] = *(uint4*)out1;
            *(uint4*)&xs[r][64 + q * 16] = *(uint4*)out2;
            *(uint4*)&xs[r][64 + q * 16 + 8] = *(uint4*)out3;
        } else {
            const uint4 z4 = {0, 0, 0, 0};
            *(uint4*)&xs[r][q * 16] = z4;
            *(uint4*)&xs[r][q * 16 + 8] = z4;
            *(uint4*)&xs[r][64 + q * 16] = z4;
            *(uint4*)&xs[r][64 + q * 16 + 8] = z4;
        }
        __syncthreads();

        f32x4 acc[4];
#pragma unroll
        for (int c = 0; c < 4; ++c) acc[c] = (f32x4){bj[c], bj[c], bj[c], bj[c]};
        const ushort* arow = xs[w * 16 + fn];
#pragma unroll
        for (int s = 0; s < 4; ++s) {
            const bf16x8 a = *(const bf16x8*)&arow[s * 32 + quad * 8];
            acc[0] = __builtin_amdgcn_mfma_f32_16x16x32_bf16(a, Bf[s][0], acc[0], 0, 0, 0);
            acc[1] = __builtin_amdgcn_mfma_f32_16x16x32_bf16(a, Bf[s][1], acc[1], 0, 0, 0);
            acc[2] = __builtin_amdgcn_mfma_f32_16x16x32_bf16(a, Bf[s][2], acc[2], 0, 0, 0);
            acc[3] = __builtin_amdgcn_mfma_f32_16x16x32_bf16(a, Bf[s][3], acc[3], 0, 0, 0);
        }
        const int row0 = n0 + w * 16 + quad * 4;
#pragma unroll
        for (int reg = 0; reg < 4; ++reg) {
            const int er = row0 + reg;
            if (er < NN) {
#pragma unroll
                for (int c = 0; c < 4; ++c) {
                    const ushort ub = f2u(acc[c][reg]);
                    z[(size_t)er * D + c * 16 + fn] = ub;
                    const float f = u2f(ub);
                    ps[c] += f; pq[c] += f * f;
                }
            }
        }
    }
    __syncthreads();
#pragma unroll
    for (int c = 0; c < 4; ++c) {
        ps[c] += __shfl_xor(ps[c], 16, 64); ps[c] += __shfl_xor(ps[c], 32, 64);
        pq[c] += __shfl_xor(pq[c], 16, 64); pq[c] += __shfl_xor(pq[c], 32, 64);
    }
    if (quad == 0) {
#pragma unroll
        for (int c = 0; c < 4; ++c) {
            sred[w][0][c * 16 + fn] = ps[c];
            sred[w][1][c * 16 + fn] = pq[c];
        }
    }
    __syncthreads();
    if (tid < 128) {
        const int col = tid & 63, which = tid >> 6;
        const float s = sred[0][which][col] + sred[1][which][col] +
                        sred[2][which][col] + sred[3][which][col];
        atomicAdd(&st[which * 64 + col], s);
    }
}

// ---------------------------------------------------------------------------
// h += relu(BN(z)) ; hb = bf16(h)
// ---------------------------------------------------------------------------
__global__ __launch_bounds__(256) void k_upd3(
    const ushort* __restrict__ z, const float* __restrict__ gg, const float* __restrict__ be,
    const float* __restrict__ st, float* __restrict__ h, ushort* __restrict__ hb)
{
    __shared__ float sal[D], sbe[D];
    const int tid = threadIdx.x;
    if (tid < D) {
        const float m = st[tid] * (1.f / NN);
        const float v = st[D + tid] * (1.f / NN) - m * m;
        const float a = rsqrtf(v + EPSB) * gg[tid];
        sal[tid] = a;
        sbe[tid] = be[tid] - m * a;
    }
    __syncthreads();
    const int j = tid & 63;
    const float al = sal[j], bt = sbe[j];
    for (int i = blockIdx.x * 256 + tid; i < NN * D; i += gridDim.x * 256) {
        const float v = h[i] + fmaxf(fmaf(u2f(z[i]), al, bt), 0.f);
        h[i] = v;
        hb[i] = f2u(v);
    }
}

// ---------------------------------------------------------------------------
// node_out = h @ node_w + node_b ; hsum += column sums of h ; copy h to d_out
// ---------------------------------------------------------------------------
__global__ __launch_bounds__(256) void k_nodeout(
    const float* __restrict__ h, const float* __restrict__ nw, const float* __restrict__ nb,
    float* __restrict__ node_out, float* __restrict__ h_out, float* __restrict__ hsum)
{
    __shared__ float hs[64][65];
    __shared__ float snw[D * NOD];
    __shared__ float snb[NOD];
    __shared__ float red[4][D];
    const int tid = threadIdx.x;
    for (int i = tid; i < D * NOD; i += 256) snw[i] = nw[i];
    if (tid < NOD) snb[tid] = nb[tid];
    const int j = tid & 63, g = tid >> 6;
    float cs = 0.f;
    for (int n0 = blockIdx.x * 64; n0 < NN; n0 += gridDim.x * 64) {
        __syncthreads();
        for (int r = g; r < 64; r += 4) {
            const int n = n0 + r;
            float v = 0.f;
            if (n < NN) { v = h[n * D + j]; h_out[n * D + j] = v; }
            hs[r][j] = v;
        }
        __syncthreads();
        for (int r = g; r < 64; r += 4) cs += hs[r][j];
        for (int it = tid; it < 64 * NOD; it += 256) {
            const int r = it / NOD, c = it - r * NOD;
            const int n = n0 + r;
            if (n < NN) {
                float a = snb[c];
#pragma unroll 16
                for (int k = 0; k < D; ++k) a += hs[r][k] * snw[k * NOD + c];
                node_out[n * NOD + c] = a;
            }
        }
    }
    red[g][j] = cs;
    __syncthreads();
    if (tid < D) atomicAdd(&hsum[tid], red[0][tid] + red[1][tid] + red[2][tid] + red[3][tid]);
}

__global__ void k_graphout(const float* __restrict__ hsum, const float* __restrict__ gw,
                           const float* __restrict__ gb, float* __restrict__ out)
{
    const int j = threadIdx.x;  // 64 threads
    float v = hsum[j] * (1.f / NN) * gw[j];
#pragma unroll
    for (int off = 32; off > 0; off >>= 1) v += __shfl_down(v, off, 64);
    if (j == 0) out[0] = v + gb[0];
}

// ---------------------------------------------------------------------------
extern "C" void kernel_launch(void* const* d_in, const int* in_sizes, int n_in,
                              void* d_out, int out_size, void* d_ws, size_t ws_size,
                              hipStream_t stream)
{
    (void)in_sizes; (void)n_in; (void)out_size; (void)ws_size;
    const float* x        = (const float*)d_in[0];
    const int*   ei       = (const int*)  d_in[1];
    const float* ea       = (const float*)d_in[2];
    const float* prev_h   = (const float*)d_in[3];
    const float* lin_in_w = (const float*)d_in[4];
    const float* lin_in_b = (const float*)d_in[5];
    const float* hist_w   = (const float*)d_in[6];
    const float* hist_b   = (const float*)d_in[7];
    const float* msg_w1   = (const float*)d_in[8];
    const float* msg_b1   = (const float*)d_in[9];
    const float* msg_g1   = (const float*)d_in[10];
    const float* msg_be1  = (const float*)d_in[11];
    const float* msg_w2   = (const float*)d_in[12];
    const float* msg_b2   = (const float*)d_in[13];
    const float* msg_g2   = (const float*)d_in[14];
    const float* msg_be2  = (const float*)d_in[15];
    const float* upd_w1   = (const float*)d_in[16];
    const float* upd_b1   = (const float*)d_in[17];
    const float* upd_g1   = (const float*)d_in[18];
    const float* upd_be1  = (const float*)d_in[19];
    const float* upd_w2   = (const float*)d_in[20];
    const float* upd_b2   = (const float*)d_in[21];
    const float* upd_g2   = (const float*)d_in[22];
    const float* upd_be2  = (const float*)d_in[23];
    const float* graph_w  = (const float*)d_in[24];
    const float* graph_b  = (const float*)d_in[25];
    const float* node_w   = (const float*)d_in[26];
    const float* node_b   = (const float*)d_in[27];

    const int* src = ei;        // edge_index[0]
    const int* dst = ei + NE;   // edge_index[1]

    float* out       = (float*)d_out;
    float* graph_out = out;                  // [1]
    float* node_out  = out + 1;              // [N*NO]
    float* h_out     = out + 1 + NN * NOD;   // [N*D]

    char* ws = (char*)d_ws;
    size_t off = 0;
    ushort* y    = (ushort*)(ws + off); off += (size_t)NE * D * sizeof(ushort);  // 64 MB
    float*  aggr = (float*) (ws + off); off += (size_t)NN * D * sizeof(float);   // 12.8 MB
    ushort* z    = (ushort*)(ws + off); off += (size_t)NN * D * sizeof(ushort);  // 6.4 MB
    float*  h    = (float*) (ws + off); off += (size_t)NN * D * sizeof(float);   // 12.8 MB
    ushort* hb   = (ushort*)(ws + off); off += (size_t)NN * D * sizeof(ushort);  // 6.4 MB
    float* stats = (float*)(ws + off);   // [NL][4][2][D] then hsum[D]
    float* hsum  = stats + NL * 4 * 2 * D;
    const size_t stats_bytes = (NL * 4 * 2 * D + D) * sizeof(float);

    hipMemsetAsync(stats, 0, stats_bytes, stream);
    k_input<<<512, 256, 0, stream>>>(x, prev_h, lin_in_w, lin_in_b, hist_w, hist_b, h, hb);

    for (int l = 0; l < NL; ++l) {
        float* st_m1 = stats + (l * 4 + 0) * 2 * D;
        float* st_m2 = stats + (l * 4 + 1) * 2 * D;
        float* st_u1 = stats + (l * 4 + 2) * 2 * D;
        float* st_u2 = stats + (l * 4 + 3) * 2 * D;
        k_msg1<<<1024, 256, 0, stream>>>(hb, src, dst, ea,
                                         msg_w1 + (size_t)l * K1 * D, msg_b1 + l * D, y, st_m1);
        k_mlp2b<<<1024, 256, 0, stream>>>(y, y,
                                          msg_w2 + (size_t)l * D * D, msg_b2 + l * D,
                                          msg_g1 + l * D, msg_be1 + l * D,
                                          st_m1, st_m2, NE, 1.f / NE);
        hipMemsetAsync(aggr, 0, (size_t)NN * D * sizeof(float), stream);
        k_aggr<<<2048, 256, 0, stream>>>(y, dst, msg_g2 + l * D, msg_be2 + l * D, st_m2, aggr);
        k_upd1<<<782, 256, 0, stream>>>(h, aggr,
                                        upd_w1 + (size_t)l * KU * D, upd_b1 + l * D, z, st_u1);
        k_mlp2b<<<782, 256, 0, stream>>>(z, z,
                                         upd_w2 + (size_t)l * D * D, upd_b2 + l * D,
                                         upd_g1 + l * D, upd_be1 + l * D,
                                         st_u1, st_u2, NN, 1.f / NN);
        k_upd3<<<1024, 256, 0, stream>>>(z, upd_g2 + l * D, upd_be2 + l * D, st_u2, h, hb);
    }

    k_nodeout<<<782, 256, 0, stream>>>(h, node_w, node_b, node_out, h_out, hsum);
    k_graphout<<<1, 64, 0, stream>>>(hsum, graph_w, graph_b, graph_out);
}